// Round 3
// baseline (1410.212 us; speedup 1.0000x reference)
//
#include <hip/hip_runtime.h>
#include <hip/hip_bf16.h>
#include <cstdint>

// CrossAttention: out = softmax((XqWq)(XkWk)^T per-token over heads) (XvWv) @ Wo + bo
// N=32768, D=512, H=8, DH=4096.
//
// Round 7: multi-tile persistent GEMM blocks. K=512 gives only NT=8 K-tiles,
// so the 8-phase pipeline spent ~50% in fill/drain (MfmaUtil 31% vs m201's
// 62%). Now each proj block computes NC=6 output tiles (z in {0,1,2} x
// bx in {b0,b0+8}) with a UNIFORM schedule: the former tail phases stage the
// next sub-tile's buffers, so the pipeline never drains (NT_eff=48, one
// prologue + one drain per block). Grid (8,32) = 256 blocks = exactly 1/CU;
// gridDim.x=8 makes default round-robin dispatch pin each b0 to one XCD ->
// B working set 1.6 MB, L2-resident. Per-j address deltas are scalar
// (SGPR) to avoid VGPR growth (at 252/256 budget). Trailing vmcnt(0)
// drains clamped final prefetches before endpgm (LDS reuse hazard).

typedef unsigned short u16;
typedef unsigned int u32;
typedef __bf16 bf16x8 __attribute__((ext_vector_type(8)));
typedef float f32x4 __attribute__((ext_vector_type(4)));

#define DEVI __device__ __forceinline__

DEVI float b2f(u16 u) {
    union { u32 i; float f; } c; c.i = ((u32)u) << 16; return c.f;
}
DEVI u16 f2b(float f) {  // RNE
    union { float f; u32 i; } c; c.f = f;
    return (u16)((c.i + 0x7FFFu + ((c.i >> 16) & 1u)) >> 16);
}
DEVI float asf(u32 x) { union { u32 i; float f; } c; c.i = x; return c.f; }

DEVI void async16(const u16* g, u16* l) {
    __builtin_amdgcn_global_load_lds(
        (const __attribute__((address_space(1))) u32*)g,
        (__attribute__((address_space(3))) u32*)l, 16, 0, 0);
}

// ---------------- prep kernels ----------------

__global__ __launch_bounds__(256) void cvt3_bf16(
    const float* __restrict__ a, const float* __restrict__ b,
    const float* __restrict__ c, u16* __restrict__ out, long ostride) {
    const float* in = (blockIdx.z == 0) ? a : (blockIdx.z == 1) ? b : c;
    u16* o = out + (long)blockIdx.z * ostride;
    const int i = blockIdx.x * 256 + threadIdx.x;
    const float4 x = ((const float4*)in)[2 * i];
    const float4 y = ((const float4*)in)[2 * i + 1];
    union { u16 u[8]; uint4 v; } r;
    r.u[0] = f2b(x.x); r.u[1] = f2b(x.y); r.u[2] = f2b(x.z); r.u[3] = f2b(x.w);
    r.u[4] = f2b(y.x); r.u[5] = f2b(y.y); r.u[6] = f2b(y.z); r.u[7] = f2b(y.w);
    ((uint4*)o)[i] = r.v;
}

__global__ void transpose_cvt(const float* __restrict__ in, u16* __restrict__ out,
                              int R, int C) {
    __shared__ float tile[32][33];
    const int c0 = blockIdx.x * 32, r0 = blockIdx.y * 32;
    const int x = threadIdx.x, y = threadIdx.y;
#pragma unroll
    for (int i = 0; i < 4; ++i) {
        const int r = y + i * 8;
        tile[x][r] = in[(long)(r0 + r) * C + c0 + x];
    }
    __syncthreads();
#pragma unroll
    for (int i = 0; i < 4; ++i) {
        const int c = y + i * 8;
        out[(long)(c0 + c) * R + r0 + x] = f2b(tile[c][x]);
    }
}

// ---------------- GEMM: C[M][N] = A[M][K] * BT[N][K]^T (+bias if F32OUT) -------
// 256x256 tile, 8-phase schedule, NC sub-tiles per block (uniform pipeline).
// K multiple of 128 (NT even, >= 4).

#define VM4 asm volatile("s_waitcnt vmcnt(4)" ::: "memory")
#define VM0 asm volatile("s_waitcnt vmcnt(0)" ::: "memory")
#define LGKM0 asm volatile("s_waitcnt lgkmcnt(0)" ::: "memory")
#define NOOP ((void)0)

// stage half h (128 rows) of K-tile t (parity t&1 picks buf) from base+off
#define STAGE_A(t, h, off)                                                \
    do {                                                                  \
        const u16* _s = Ab + (off) + laneOff + (long)(h) * 128 * K +      \
                        (long)(t) * 64;                                   \
        u16* _d = As + (((t) & 1) * 16384) + (h) * 8192 + wave * 512;     \
        async16(_s, _d);                                                  \
        async16(_s + 64 * (long)K, _d + 4096);                            \
    } while (0)

#define STAGE_B(t, h, off)                                                \
    do {                                                                  \
        const u16* _s = Bb + (off) + laneOff + (long)(h) * 128 * K +      \
                        (long)(t) * 64;                                   \
        u16* _d = Bs + (((t) & 1) * 16384) + (h) * 8192 + wave * 512;     \
        async16(_s, _d);                                                  \
        async16(_s + 64 * (long)K, _d + 4096);                            \
    } while (0)

#define PHASE(c, P, STG, VW)                                                   \
    {                                                                          \
        const u16* _sA = As + (c) * 16384;                                     \
        const u16* _sB = Bs + (c) * 16384;                                     \
        bf16x8 a00 = *(const bf16x8*)(_sA + arow_u + (2 * (P)) * 1024 + s0);   \
        bf16x8 a01 = *(const bf16x8*)(_sA + arow_u + (2 * (P)) * 1024 + s1);   \
        bf16x8 a10 = *(const bf16x8*)(_sA + arow_u + (2 * (P) + 1) * 1024 + s0); \
        bf16x8 a11 = *(const bf16x8*)(_sA + arow_u + (2 * (P) + 1) * 1024 + s1); \
        if ((P) == 0) {                                                        \
            _Pragma("unroll") for (int n = 0; n < 4; ++n) {                    \
                bfr[n][0] = *(const bf16x8*)(_sB + brow_u + n * 1024 + s0);    \
                bfr[n][1] = *(const bf16x8*)(_sB + brow_u + n * 1024 + s1);    \
            }                                                                  \
        }                                                                      \
        STG;                                                                   \
        __builtin_amdgcn_s_barrier();                                          \
        LGKM0;                                                                 \
        __builtin_amdgcn_s_setprio(1);                                         \
        _Pragma("unroll") for (int n = 0; n < 4; ++n) {                        \
            acc[2 * (P)][n] = __builtin_amdgcn_mfma_f32_16x16x32_bf16(         \
                a00, bfr[n][0], acc[2 * (P)][n], 0, 0, 0);                     \
            acc[2 * (P)][n] = __builtin_amdgcn_mfma_f32_16x16x32_bf16(         \
                a01, bfr[n][1], acc[2 * (P)][n], 0, 0, 0);                     \
            acc[2 * (P) + 1][n] = __builtin_amdgcn_mfma_f32_16x16x32_bf16(     \
                a10, bfr[n][0], acc[2 * (P) + 1][n], 0, 0, 0);                 \
            acc[2 * (P) + 1][n] = __builtin_amdgcn_mfma_f32_16x16x32_bf16(     \
                a11, bfr[n][1], acc[2 * (P) + 1][n], 0, 0, 0);                 \
        }                                                                      \
        __builtin_amdgcn_s_setprio(0);                                         \
        VW;                                                                    \
        __builtin_amdgcn_s_barrier();                                          \
    }

// MODE 0: generic, one tile per block, z from blockIdx.z, XCD swizzle.
// MODE 1: proj z-flattened: grid (8, M/256); block does NC=6 sub-tiles
//         j -> (z = j>>1, bx = b0 + (j&1)*8). A panel reused across j&1.
template <int F32OUT, int MODE>
__global__ __launch_bounds__(512, 2) void gemm256(
    const u16* __restrict__ Ab, const u16* __restrict__ Bb,
    void* __restrict__ Cv, const float* __restrict__ bias,
    int M, int N, int K, long sAz, long sBz, long sCz) {
    __shared__ u16 As[2 * 16384];   // 2 bufs x [256 rows][64 k]
    __shared__ u16 Bs[2 * 16384];
    (void)M;
    const int tid = threadIdx.x;
    const int wave = tid >> 6, lane = tid & 63;

    int b0, by;
    long zoffA = 0, zoffB = 0, zoffC = 0;
    if (MODE == 0) {
        const int gx = gridDim.x, nwg = gx * gridDim.y;
        const int b = blockIdx.y * gx + blockIdx.x;
        if ((nwg & 7) == 0) {
            const int cpx = nwg >> 3;
            const int w = (b & 7) * cpx + (b >> 3);
            b0 = w % gx; by = w / gx;
        } else { b0 = blockIdx.x; by = blockIdx.y; }
        const int z = blockIdx.z;
        zoffA = (long)z * sAz; zoffB = (long)z * sBz; zoffC = (long)z * sCz;
    } else {
        b0 = blockIdx.x; by = blockIdx.y;
    }
    const long row0 = (long)by * 256;

    const int mrow = lane & 15, quad = lane >> 4;
    const int wr = wave >> 2, wc = wave & 3;       // 2 x 4 wave grid
    const int s0 = ((quad ^ (mrow & 7)) << 3);
    const int s1 = (((4 | quad) ^ (mrow & 7)) << 3);
    const int arow_u = (wr * 128 + mrow) * 64;
    const int brow_u = (wc * 64 + mrow) * 64;

    // staging lane offset (same for A and B; k-group XOR pre-swizzle)
    const int sr = tid >> 3;
    const int skg = ((tid & 7) ^ (sr & 7)) << 3;
    const long laneOff = (long)sr * K + skg;

    f32x4 acc[8][4] = {};
    bf16x8 bfr[4][2];

    const int NC = (MODE == 1) ? 6 : 1;
    const int NT = K >> 6;   // even, >= 4
    const int NI = NT >> 1;

    // per-sub-tile scalar offsets
    long oA, oB, colj, oA2, oB2, colj2;
    {
        if (MODE == 1) {
            colj = (long)b0 * 256;
            oA = row0 * (long)K;
            oB = colj * (long)K;
        } else {
            colj = (long)b0 * 256;
            oA = zoffA + row0 * (long)K;
            oB = zoffB + colj * (long)K;
        }
    }

    // prologue: j=0 tile0 fully + tile1's B halves
    STAGE_A(0, 0, oA); STAGE_A(0, 1, oA);
    STAGE_B(0, 0, oB); STAGE_B(0, 1, oB);
    STAGE_B(1, 0, oB); STAGE_B(1, 1, oB);
    VM4;
    __builtin_amdgcn_s_barrier();

#pragma unroll 1
    for (int j = 0; j < NC; ++j) {
        {   // offsets of the NEXT sub-tile (clamped at the end; clamped
            // stages re-read valid memory and are drained by final VM0)
            const int jn = (j + 1 < NC) ? j + 1 : j;
            if (MODE == 1) {
                const int zn = jn >> 1;
                colj2 = (long)(b0 + ((jn & 1) << 3)) * 256;
                oA2 = (long)zn * sAz + row0 * (long)K;
                oB2 = (long)zn * sBz + colj2 * (long)K;
            } else { oA2 = oA; oB2 = oB; colj2 = colj; }
        }
#pragma unroll 1
        for (int it = 0; it < NI - 1; ++it) {
            const int t1 = 2 * it + 1;
            PHASE(0, 0, STAGE_A(t1, 0, oA), NOOP);
            PHASE(0, 1, STAGE_A(t1, 1, oA), NOOP);
            PHASE(0, 2, STAGE_B(t1 + 1, 0, oB), NOOP);
            PHASE(0, 3, STAGE_B(t1 + 1, 1, oB), VM4);
            PHASE(1, 0, STAGE_A(t1 + 1, 0, oA), NOOP);
            PHASE(1, 1, STAGE_A(t1 + 1, 1, oA), NOOP);
            PHASE(1, 2, STAGE_B(t1 + 2, 0, oB), NOOP);
            PHASE(1, 3, STAGE_B(t1 + 2, 1, oB), VM4);
        }
        {   // last pair: tiles NT-2 (buf0), NT-1 (buf1); stage next j's 0,1
            PHASE(0, 0, STAGE_A(NT - 1, 0, oA), NOOP);
            PHASE(0, 1, STAGE_A(NT - 1, 1, oA), NOOP);
            PHASE(0, 2, STAGE_B(0, 0, oB2), NOOP);
            PHASE(0, 3, STAGE_B(0, 1, oB2), VM4);
            PHASE(1, 0, STAGE_A(0, 0, oA2), NOOP);
            PHASE(1, 1, STAGE_A(0, 1, oA2), NOOP);
            PHASE(1, 2, STAGE_B(1, 0, oB2), NOOP);
            PHASE(1, 3, STAGE_B(1, 1, oB2), VM4);
        }

        // epilogue for sub-tile j: D[row=(quad*4+rr)][col=mrow] per 16x16 tile
        {
            const long wrow = row0 + wr * 128;
            const long wcol = colj + wc * 64;
            const long cz = (MODE == 1) ? (long)(j >> 1) * sCz : zoffC;
            if (F32OUT) {
                float* C = (float*)Cv + cz;
                float bv[4];
#pragma unroll
                for (int n = 0; n < 4; ++n) bv[n] = bias[wcol + n * 16 + mrow];
#pragma unroll
                for (int m = 0; m < 8; ++m) {
                    const long r = wrow + m * 16 + quad * 4;
#pragma unroll
                    for (int n = 0; n < 4; ++n) {
                        const long c = wcol + n * 16 + mrow;
#pragma unroll
                        for (int rr = 0; rr < 4; ++rr)
                            C[(r + rr) * (long)N + c] = acc[m][n][rr] + bv[n];
                    }
                }
            } else {
                u16* C = (u16*)Cv + cz;
#pragma unroll
                for (int m = 0; m < 8; ++m) {
                    const long r = wrow + m * 16 + quad * 4;
#pragma unroll
                    for (int n = 0; n < 4; ++n) {
                        const long c = wcol + n * 16 + mrow;
#pragma unroll
                        for (int rr = 0; rr < 4; ++rr)
                            C[(r + rr) * (long)N + c] = f2b(acc[m][n][rr]);
                    }
                }
            }
            if (j + 1 < NC) {   // zero acc for next sub-tile
#pragma unroll
                for (int m = 0; m < 8; ++m)
#pragma unroll
                    for (int n = 0; n < 4; ++n)
                        acc[m][n] = (f32x4){0.f, 0.f, 0.f, 0.f};
            }
        }
        oA = oA2; oB = oB2; colj = colj2;
    }
    VM0;   // drain clamped trailing prefetches before LDS is released
}

#undef PHASE
#undef STAGE_A
#undef STAGE_B

// ---------------- per-token attention over heads (vectorized) ----------------

DEVI float dot8(uint4 a, uint4 b) {
    const u32* pa = (const u32*)&a;
    const u32* pb = (const u32*)&b;
    float s = 0.f;
#pragma unroll
    for (int w = 0; w < 4; ++w) {
        s = fmaf(asf(pa[w] << 16), asf(pb[w] << 16), s);
        s = fmaf(asf(pa[w] & 0xFFFF0000u), asf(pb[w] & 0xFFFF0000u), s);
    }
    return s;
}

DEVI void acc8(float* o, uint4 v, float p) {
    const u32* pv = (const u32*)&v;
#pragma unroll
    for (int w = 0; w < 4; ++w) {
        o[2 * w]     = fmaf(p, asf(pv[w] << 16), o[2 * w]);
        o[2 * w + 1] = fmaf(p, asf(pv[w] & 0xFFFF0000u), o[2 * w + 1]);
    }
}

__global__ __launch_bounds__(256) void attn_kernel(
    const u16* __restrict__ Qg, const u16* __restrict__ Kg,
    const u16* __restrict__ Vg, u16* __restrict__ Og) {
    __shared__ uint4 sQ[8 * 65];   // padded: row stride 65 uint4
    __shared__ uint4 sK[8 * 65];
    __shared__ uint4 sV[512];      // unpadded: 8 x 64
    __shared__ float part[4][64];
    __shared__ float logitS[64];
    __shared__ float probS[64];
    const int t = threadIdx.x;
    const long base = (long)blockIdx.x * 4096;

    const uint4* q4 = (const uint4*)(Qg + base);
    const uint4* k4 = (const uint4*)(Kg + base);
    const uint4* v4 = (const uint4*)(Vg + base);
    {
        const int r0 = t >> 6, c0 = t & 63;
        sQ[r0 * 65 + c0] = q4[t];
        sK[r0 * 65 + c0] = k4[t];
        const int r1 = r0 + 4;
        sQ[r1 * 65 + c0] = q4[t + 256];
        sK[r1 * 65 + c0] = k4[t + 256];
        sV[t] = v4[t];
        sV[t + 256] = v4[t + 256];
    }
    __syncthreads();

    {   // logits: pair (h,g) x 4 chunks of 128 d (16 uint4 each)
        const int pr = t & 63, ch = t >> 6;
        const int h = pr >> 3, g = pr & 7;
        const uint4* qp = sQ + h * 65 + ch * 16;
        const uint4* kp = sK + g * 65 + ch * 16;
        float s = 0.f;
#pragma unroll
        for (int i = 0; i < 16; ++i) s += dot8(qp[i], kp[i]);
        part[ch][pr] = s;
    }
    __syncthreads();
    if (t < 64) logitS[t] = part[0][t] + part[1][t] + part[2][t] + part[3][t];
    __syncthreads();
    if (t < 8) {   // softmax row h=t over g
        float m = logitS[t * 8];
#pragma unroll
        for (int g = 1; g < 8; ++g) m = fmaxf(m, logitS[t * 8 + g]);
        float e[8], sum = 0.f;
#pragma unroll
        for (int g = 0; g < 8; ++g) { e[g] = __expf(logitS[t * 8 + g] - m); sum += e[g]; }
        const float inv = 1.f / sum;
#pragma unroll
        for (int g = 0; g < 8; ++g) probS[t * 8 + g] = e[g] * inv;
    }
    __syncthreads();

    const int hh = t >> 5, c = t & 31;
    float p[8];
#pragma unroll
    for (int g = 0; g < 8; ++g) p[g] = probS[hh * 8 + g];
    float o0[8], o1[8];
#pragma unroll
    for (int j = 0; j < 8; ++j) { o0[j] = 0.f; o1[j] = 0.f; }
#pragma unroll
    for (int g = 0; g < 8; ++g) {
        const uint4 va = sV[g * 64 + c];
        const uint4 vb = sV[g * 64 + 32 + c];
        acc8(o0, va, p[g]);
        acc8(o1, vb, p[g]);
    }
    union { u16 u[8]; uint4 v; } ob;
#pragma unroll
    for (int j = 0; j < 8; ++j) ob.u[j] = f2b(o0[j]);
    *(uint4*)(Og + base + hh * 512 + c * 8) = ob.v;
#pragma unroll
    for (int j = 0; j < 8; ++j) ob.u[j] = f2b(o1[j]);
    *(uint4*)(Og + base + hh * 512 + 256 + c * 8) = ob.v;
}

// ---------------- launch ----------------

extern "C" void kernel_launch(void* const* d_in, const int* in_sizes, int n_in,
                              void* d_out, int out_size, void* d_ws, size_t ws_size,
                              hipStream_t stream) {
    const float* Xq = (const float*)d_in[0];
    const float* Xk = (const float*)d_in[1];
    const float* Xv = (const float*)d_in[2];
    const float* Wq = (const float*)d_in[3];
    const float* Wk = (const float*)d_in[4];
    const float* Wv = (const float*)d_in[5];
    const float* Wo = (const float*)d_in[6];
    const float* bo = (const float*)d_in[7];

    const int N = 32768;
    const size_t W = 16777216ull;      // transposed weights
    const size_t AO = 268435456ull;    // full-N attn_out (Plan A)

    int McA = 0;
    for (int m = 8192; m >= 1024; m >>= 1)
        if (W + AO + (size_t)m * 27648ull <= ws_size) { McA = m; break; }

    char* ws = (char*)d_ws;
    u16* WqT = (u16*)(ws);                    // [4096][512] x3 contiguous
    u16* WoT = (u16*)(ws + 12582912ull);      // [512][4096]

    dim3 tb(32, 8);
    transpose_cvt<<<dim3(128, 16), tb, 0, stream>>>(Wq, WqT, 512, 4096);
    transpose_cvt<<<dim3(128, 16), tb, 0, stream>>>(Wk, WqT + 2097152, 512, 4096);
    transpose_cvt<<<dim3(128, 16), tb, 0, stream>>>(Wv, WqT + 4194304, 512, 4096);
    transpose_cvt<<<dim3(16, 128), tb, 0, stream>>>(Wo, WoT, 4096, 512);

    if (McA) {
        // ---- Plan A ----
        const int Mc = McA;
        u16* Ao  = (u16*)(ws + W);
        u16* Xb  = (u16*)(ws + W + AO);           // 3x [Mc][512]
        u16* Qc  = Xb + (size_t)3 * Mc * 512;     // 3x [Mc][4096]
        u16* Kc  = Qc + (size_t)Mc * 4096;
        u16* Vc  = Kc + (size_t)Mc * 4096;
        const dim3 gProj(8, Mc / 256, 1);         // MODE=1: 6 sub-tiles/block
        for (int m0 = 0; m0 < N; m0 += Mc) {
            const long xoff = (long)m0 * 512;
            cvt3_bf16<<<dim3(Mc / 4, 1, 3), 256, 0, stream>>>(
                Xq + xoff, Xk + xoff, Xv + xoff, Xb, (long)Mc * 512);
            gemm256<0, 1><<<gProj, 512, 0, stream>>>(Xb, WqT, Qc, nullptr,
                                                     Mc, 4096, 512,
                                                     (long)Mc * 512, 2097152L,
                                                     (long)Mc * 4096);
            attn_kernel<<<Mc, 256, 0, stream>>>(Qc, Kc, Vc, Ao + (long)m0 * 4096);
        }
        gemm256<1, 0><<<dim3(2, 128, 1), 512, 0, stream>>>(
            Ao, WoT, d_out, bo, N, 512, 4096, 0L, 0L, 0L);
    } else {
        // ---- Plan B (streaming) ----
        int Mc = 8192;
        while (Mc > 256 && W + (size_t)Mc * 27648ull > ws_size) Mc >>= 1;
        if (W + (size_t)Mc * 27648ull > ws_size) return;
        u16* Xb = (u16*)(ws + W);
        u16* Qc = Xb + (size_t)3 * Mc * 512;
        u16* Kc = Qc + (size_t)Mc * 4096;
        u16* Vc = Kc + (size_t)Mc * 4096;
        const dim3 gProj(8, Mc / 256, 1);
        const dim3 gOut(2, Mc / 256, 1);
        for (int m0 = 0; m0 < N; m0 += Mc) {
            const long xoff = (long)m0 * 512;
            cvt3_bf16<<<dim3(Mc / 4, 1, 3), 256, 0, stream>>>(
                Xq + xoff, Xk + xoff, Xv + xoff, Xb, (long)Mc * 512);
            gemm256<0, 1><<<gProj, 512, 0, stream>>>(Xb, WqT, Qc, nullptr,
                                                     Mc, 4096, 512,
                                                     (long)Mc * 512, 2097152L,
                                                     (long)Mc * 4096);
            attn_kernel<<<Mc, 256, 0, stream>>>(Qc, Kc, Vc, Qc);
            gemm256<1, 0><<<gOut, 512, 0, stream>>>(Qc, WoT, (float*)d_out + xoff, bo,
                                                    Mc, 512, 4096, 0L, 0L, 0L);
        }
    }
}

// Round 4
// 1370.214 us; speedup vs baseline: 1.0292x; 1.0292x over previous
//
#include <hip/hip_runtime.h>
#include <hip/hip_bf16.h>
#include <cstdint>

// CrossAttention: out = softmax((XqWq)(XkWk)^T per-token over heads) (XvWv) @ Wo + bo
// N=32768, D=512, H=8, DH=4096.
//
// Round 8:
//  - GEMM: reverted to round-2 structure (256x256 8-phase, MODE-0 grid with
//    XCD swizzle). Round-3's persistent MODE-1 pinned COLUMNS to XCDs ->
//    every XCD re-fetched all of A (FETCH 110->207 MB, MfmaUtil 31->26%).
//  - attn: rebuilt staging + softmax:
//      * global_load_lds staging (6 async16/thread, no VGPR round trip);
//      * Q/K stored with per-row XOR slot swizzle (slot s of row r holds
//        col s^r), achieved by pre-swizzling the GLOBAL source address
//        (LDS dest stays linear -> compatible with global_load_lds);
//        QK-phase row reads hit 8 distinct bank groups, conflict-free,
//        no padding. V linear (PV reads broadcast/contiguous).
//      * softmax: 64-lane shuffle reduce (was 8-thread serial/divergent).
//      * 3 barriers (was 4).

typedef unsigned short u16;
typedef unsigned int u32;
typedef __bf16 bf16x8 __attribute__((ext_vector_type(8)));
typedef float f32x4 __attribute__((ext_vector_type(4)));

#define DEVI __device__ __forceinline__

DEVI float b2f(u16 u) {
    union { u32 i; float f; } c; c.i = ((u32)u) << 16; return c.f;
}
DEVI u16 f2b(float f) {  // RNE
    union { float f; u32 i; } c; c.f = f;
    return (u16)((c.i + 0x7FFFu + ((c.i >> 16) & 1u)) >> 16);
}
DEVI float asf(u32 x) { union { u32 i; float f; } c; c.i = x; return c.f; }

DEVI void async16(const u16* g, u16* l) {
    __builtin_amdgcn_global_load_lds(
        (const __attribute__((address_space(1))) u32*)g,
        (__attribute__((address_space(3))) u32*)l, 16, 0, 0);
}

// ---------------- prep kernels ----------------

__global__ __launch_bounds__(256) void cvt3_bf16(
    const float* __restrict__ a, const float* __restrict__ b,
    const float* __restrict__ c, u16* __restrict__ out, long ostride) {
    const float* in = (blockIdx.z == 0) ? a : (blockIdx.z == 1) ? b : c;
    u16* o = out + (long)blockIdx.z * ostride;
    const int i = blockIdx.x * 256 + threadIdx.x;
    const float4 x = ((const float4*)in)[2 * i];
    const float4 y = ((const float4*)in)[2 * i + 1];
    union { u16 u[8]; uint4 v; } r;
    r.u[0] = f2b(x.x); r.u[1] = f2b(x.y); r.u[2] = f2b(x.z); r.u[3] = f2b(x.w);
    r.u[4] = f2b(y.x); r.u[5] = f2b(y.y); r.u[6] = f2b(y.z); r.u[7] = f2b(y.w);
    ((uint4*)o)[i] = r.v;
}

__global__ void transpose_cvt(const float* __restrict__ in, u16* __restrict__ out,
                              int R, int C) {
    __shared__ float tile[32][33];
    const int c0 = blockIdx.x * 32, r0 = blockIdx.y * 32;
    const int x = threadIdx.x, y = threadIdx.y;
#pragma unroll
    for (int i = 0; i < 4; ++i) {
        const int r = y + i * 8;
        tile[x][r] = in[(long)(r0 + r) * C + c0 + x];
    }
    __syncthreads();
#pragma unroll
    for (int i = 0; i < 4; ++i) {
        const int c = y + i * 8;
        out[(long)(c0 + c) * R + r0 + x] = f2b(tile[c][x]);
    }
}

// ---------------- GEMM: C[M][N] = A[M][K] * BT[N][K]^T (+bias if F32OUT) -------
// 256x256 tile, 8-phase schedule. K multiple of 128 (NT even, >= 4).

#define VM4 asm volatile("s_waitcnt vmcnt(4)" ::: "memory")
#define VM0 asm volatile("s_waitcnt vmcnt(0)" ::: "memory")
#define LGKM0 asm volatile("s_waitcnt lgkmcnt(0)" ::: "memory")
#define NOOP ((void)0)

#define STAGE_A(t, h)                                                     \
    do {                                                                  \
        const u16* _s = pA + (long)(h) * 128 * K + (long)(t) * 64;        \
        u16* _d = As + (((t) & 1) * 16384) + (h) * 8192 + wave * 512;     \
        async16(_s, _d);                                                  \
        async16(_s + 64 * (long)K, _d + 4096);                            \
    } while (0)

#define STAGE_B(t, h)                                                     \
    do {                                                                  \
        const u16* _s = pB + (long)(h) * 128 * K + (long)(t) * 64;        \
        u16* _d = Bs + (((t) & 1) * 16384) + (h) * 8192 + wave * 512;     \
        async16(_s, _d);                                                  \
        async16(_s + 64 * (long)K, _d + 4096);                            \
    } while (0)

#define PHASE(c, P, STG, VW)                                                   \
    {                                                                          \
        const u16* _sA = As + (c) * 16384;                                     \
        const u16* _sB = Bs + (c) * 16384;                                     \
        bf16x8 a00 = *(const bf16x8*)(_sA + arow_u + (2 * (P)) * 1024 + s0);   \
        bf16x8 a01 = *(const bf16x8*)(_sA + arow_u + (2 * (P)) * 1024 + s1);   \
        bf16x8 a10 = *(const bf16x8*)(_sA + arow_u + (2 * (P) + 1) * 1024 + s0); \
        bf16x8 a11 = *(const bf16x8*)(_sA + arow_u + (2 * (P) + 1) * 1024 + s1); \
        if ((P) == 0) {                                                        \
            _Pragma("unroll") for (int n = 0; n < 4; ++n) {                    \
                bfr[n][0] = *(const bf16x8*)(_sB + brow_u + n * 1024 + s0);    \
                bfr[n][1] = *(const bf16x8*)(_sB + brow_u + n * 1024 + s1);    \
            }                                                                  \
        }                                                                      \
        STG;                                                                   \
        __builtin_amdgcn_s_barrier();                                          \
        LGKM0;                                                                 \
        __builtin_amdgcn_s_setprio(1);                                         \
        _Pragma("unroll") for (int n = 0; n < 4; ++n) {                        \
            acc[2 * (P)][n] = __builtin_amdgcn_mfma_f32_16x16x32_bf16(         \
                a00, bfr[n][0], acc[2 * (P)][n], 0, 0, 0);                     \
            acc[2 * (P)][n] = __builtin_amdgcn_mfma_f32_16x16x32_bf16(         \
                a01, bfr[n][1], acc[2 * (P)][n], 0, 0, 0);                     \
            acc[2 * (P) + 1][n] = __builtin_amdgcn_mfma_f32_16x16x32_bf16(     \
                a10, bfr[n][0], acc[2 * (P) + 1][n], 0, 0, 0);                 \
            acc[2 * (P) + 1][n] = __builtin_amdgcn_mfma_f32_16x16x32_bf16(     \
                a11, bfr[n][1], acc[2 * (P) + 1][n], 0, 0, 0);                 \
        }                                                                      \
        __builtin_amdgcn_s_setprio(0);                                         \
        VW;                                                                    \
        __builtin_amdgcn_s_barrier();                                          \
    }

template <int F32OUT>
__global__ __launch_bounds__(512, 2) void gemm256(
    const u16* __restrict__ Ab, const u16* __restrict__ Bb,
    void* __restrict__ Cv, const float* __restrict__ bias,
    int M, int N, int K, long sAz, long sBz, long sCz) {
    __shared__ u16 As[2 * 16384];   // 2 bufs x [256 rows][64 k]
    __shared__ u16 Bs[2 * 16384];
    (void)M;
    const int tid = threadIdx.x;
    const int wave = tid >> 6, lane = tid & 63;
    const int z = blockIdx.z;
    const u16* A = Ab + (long)z * sAz;
    const u16* BT = Bb + (long)z * sBz;

    int bx, by;
    {
        const int gx = gridDim.x, nwg = gx * gridDim.y;
        const int b = blockIdx.y * gx + blockIdx.x;
        if ((nwg & 7) == 0) {
            const int cpx = nwg >> 3;
            const int w = (b & 7) * cpx + (b >> 3);
            bx = w % gx; by = w / gx;
        } else { bx = blockIdx.x; by = blockIdx.y; }
    }
    const long row0 = (long)by * 256, col0 = (long)bx * 256;

    const int mrow = lane & 15, quad = lane >> 4;
    const int wr = wave >> 2, wc = wave & 3;       // 2 x 4 wave grid
    const int s0 = ((quad ^ (mrow & 7)) << 3);
    const int s1 = (((4 | quad) ^ (mrow & 7)) << 3);
    const int arow_u = (wr * 128 + mrow) * 64;
    const int brow_u = (wc * 64 + mrow) * 64;

    const int sr = tid >> 3;
    const int skg = ((tid & 7) ^ (sr & 7)) << 3;
    const u16* pA = A + (row0 + sr) * (long)K + skg;
    const u16* pB = BT + (col0 + sr) * (long)K + skg;

    f32x4 acc[8][4] = {};
    bf16x8 bfr[4][2];

    const int NT = K >> 6;   // even, >= 4
    const int NI = NT >> 1;

    STAGE_A(0, 0); STAGE_A(0, 1); STAGE_B(0, 0); STAGE_B(0, 1);
    STAGE_B(1, 0); STAGE_B(1, 1);
    VM4;
    __builtin_amdgcn_s_barrier();

#pragma unroll 1
    for (int it = 0; it < NI - 1; ++it) {
        const int t1 = 2 * it + 1;
        PHASE(0, 0, STAGE_A(t1, 0), NOOP);
        PHASE(0, 1, STAGE_A(t1, 1), NOOP);
        PHASE(0, 2, STAGE_B(t1 + 1, 0), NOOP);
        PHASE(0, 3, STAGE_B(t1 + 1, 1), VM4);
        PHASE(1, 0, STAGE_A(t1 + 1, 0), NOOP);
        PHASE(1, 1, STAGE_A(t1 + 1, 1), NOOP);
        PHASE(1, 2, STAGE_B(t1 + 2, 0), NOOP);
        PHASE(1, 3, STAGE_B(t1 + 2, 1), VM4);
    }
    {
        const int tl = NT - 1;
        PHASE(0, 0, STAGE_A(tl, 0), NOOP);
        PHASE(0, 1, STAGE_A(tl, 1), NOOP);
        PHASE(0, 2, NOOP, NOOP);
        PHASE(0, 3, NOOP, VM0);
        PHASE(1, 0, NOOP, NOOP);
        PHASE(1, 1, NOOP, NOOP);
        PHASE(1, 2, NOOP, NOOP);
        PHASE(1, 3, NOOP, NOOP);
    }

    const long wrow = row0 + wr * 128;
    const long wcol = col0 + wc * 64;
    if (F32OUT) {
        float* C = (float*)Cv + (long)z * sCz;
        float bv[4];
#pragma unroll
        for (int n = 0; n < 4; ++n) bv[n] = bias[wcol + n * 16 + mrow];
#pragma unroll
        for (int m = 0; m < 8; ++m) {
            const long r = wrow + m * 16 + quad * 4;
#pragma unroll
            for (int n = 0; n < 4; ++n) {
                const long c = wcol + n * 16 + mrow;
#pragma unroll
                for (int rr = 0; rr < 4; ++rr)
                    C[(r + rr) * (long)N + c] = acc[m][n][rr] + bv[n];
            }
        }
    } else {
        u16* C = (u16*)Cv + (long)z * sCz;
#pragma unroll
        for (int m = 0; m < 8; ++m) {
            const long r = wrow + m * 16 + quad * 4;
#pragma unroll
            for (int n = 0; n < 4; ++n) {
                const long c = wcol + n * 16 + mrow;
#pragma unroll
                for (int rr = 0; rr < 4; ++rr)
                    C[(r + rr) * (long)N + c] = f2b(acc[m][n][rr]);
            }
        }
    }
}

#undef PHASE
#undef STAGE_A
#undef STAGE_B

// ---------------- per-token attention over heads ----------------
// one block (256 thr) per token; global_load_lds staging; Q/K XOR-swizzled
// (slot s of row r holds col s^r, via pre-swizzled global source); V linear.

DEVI float dot8(uint4 a, uint4 b) {
    const u32* pa = (const u32*)&a;
    const u32* pb = (const u32*)&b;
    float s = 0.f;
#pragma unroll
    for (int w = 0; w < 4; ++w) {
        s = fmaf(asf(pa[w] << 16), asf(pb[w] << 16), s);
        s = fmaf(asf(pa[w] & 0xFFFF0000u), asf(pb[w] & 0xFFFF0000u), s);
    }
    return s;
}

DEVI void acc8(float* o, uint4 v, float p) {
    const u32* pv = (const u32*)&v;
#pragma unroll
    for (int w = 0; w < 4; ++w) {
        o[2 * w]     = fmaf(p, asf(pv[w] << 16), o[2 * w]);
        o[2 * w + 1] = fmaf(p, asf(pv[w] & 0xFFFF0000u), o[2 * w + 1]);
    }
}

__global__ __launch_bounds__(256) void attn_kernel(
    const u16* __restrict__ Qg, const u16* __restrict__ Kg,
    const u16* __restrict__ Vg, u16* __restrict__ Og) {
    __shared__ u16 sQ[4096];   // 8 rows x 64 uint4 slots; slot s = col s^r
    __shared__ u16 sK[4096];
    __shared__ u16 sV[4096];   // linear
    __shared__ float part[4][64];
    __shared__ float probS[64];
    const int t = threadIdx.x;
    const int wave = t >> 6, lane = t & 63;
    const long base = (long)blockIdx.x * 4096;

    {   // stage: wave w covers rows w and w+4 of Q,K,V (one async16 = one row)
        const int r0 = wave, r1 = wave + 4;
        async16(Qg + base + r0 * 512 + ((lane ^ r0) << 3), sQ + r0 * 512);
        async16(Qg + base + r1 * 512 + ((lane ^ r1) << 3), sQ + r1 * 512);
        async16(Kg + base + r0 * 512 + ((lane ^ r0) << 3), sK + r0 * 512);
        async16(Kg + base + r1 * 512 + ((lane ^ r1) << 3), sK + r1 * 512);
        async16(Vg + base + r0 * 512 + (lane << 3), sV + r0 * 512);
        async16(Vg + base + r1 * 512 + (lane << 3), sV + r1 * 512);
    }
    __syncthreads();   // drains vmcnt

    {   // logits: pair (h,g) x 4 chunks of 128 d (16 uint4 each)
        const int pr = lane;
        const int h = pr >> 3, g = pr & 7;
        const uint4* q4 = (const uint4*)sQ;
        const uint4* k4 = (const uint4*)sK;
        float s = 0.f;
#pragma unroll
        for (int i = 0; i < 16; ++i) {
            const int c = wave * 16 + i;
            s += dot8(q4[h * 64 + (c ^ h)], k4[g * 64 + (c ^ g)]);
        }
        part[wave][pr] = s;
    }
    __syncthreads();

    if (t < 64) {   // softmax, 64-lane: lane=(h,g); reduce over g (8-lane groups)
        const float sl = part[0][t] + part[1][t] + part[2][t] + part[3][t];
        float m = sl;
        m = fmaxf(m, __shfl_xor(m, 1));
        m = fmaxf(m, __shfl_xor(m, 2));
        m = fmaxf(m, __shfl_xor(m, 4));
        const float e = __expf(sl - m);
        float sum = e;
        sum += __shfl_xor(sum, 1);
        sum += __shfl_xor(sum, 2);
        sum += __shfl_xor(sum, 4);
        probS[t] = e / sum;
    }
    __syncthreads();

    // PV: thread (head hh = t>>5, c = t&31) accumulates d = c*8..+7 and
    // d = 256 + c*8..+7 (V reads contiguous/broadcast, conflict-free)
    const int hh = t >> 5, c = t & 31;
    const uint4* v4 = (const uint4*)sV;
    float p[8];
#pragma unroll
    for (int g = 0; g < 8; ++g) p[g] = probS[hh * 8 + g];
    float o0[8], o1[8];
#pragma unroll
    for (int j = 0; j < 8; ++j) { o0[j] = 0.f; o1[j] = 0.f; }
#pragma unroll
    for (int g = 0; g < 8; ++g) {
        const uint4 va = v4[g * 64 + c];
        const uint4 vb = v4[g * 64 + 32 + c];
        acc8(o0, va, p[g]);
        acc8(o1, vb, p[g]);
    }
    union { u16 u[8]; uint4 v; } ob;
#pragma unroll
    for (int j = 0; j < 8; ++j) ob.u[j] = f2b(o0[j]);
    *(uint4*)(Og + base + hh * 512 + c * 8) = ob.v;
#pragma unroll
    for (int j = 0; j < 8; ++j) ob.u[j] = f2b(o1[j]);
    *(uint4*)(Og + base + hh * 512 + 256 + c * 8) = ob.v;
}

// ---------------- launch ----------------

extern "C" void kernel_launch(void* const* d_in, const int* in_sizes, int n_in,
                              void* d_out, int out_size, void* d_ws, size_t ws_size,
                              hipStream_t stream) {
    const float* Xq = (const float*)d_in[0];
    const float* Xk = (const float*)d_in[1];
    const float* Xv = (const float*)d_in[2];
    const float* Wq = (const float*)d_in[3];
    const float* Wk = (const float*)d_in[4];
    const float* Wv = (const float*)d_in[5];
    const float* Wo = (const float*)d_in[6];
    const float* bo = (const float*)d_in[7];

    const int N = 32768;
    const size_t W = 16777216ull;      // transposed weights
    const size_t AO = 268435456ull;    // full-N attn_out (Plan A)

    int McA = 0;
    for (int m = 8192; m >= 1024; m >>= 1)
        if (W + AO + (size_t)m * 27648ull <= ws_size) { McA = m; break; }

    char* ws = (char*)d_ws;
    u16* WqT = (u16*)(ws);                    // [4096][512] x3 contiguous
    u16* WoT = (u16*)(ws + 12582912ull);      // [512][4096]

    dim3 tb(32, 8);
    transpose_cvt<<<dim3(128, 16), tb, 0, stream>>>(Wq, WqT, 512, 4096);
    transpose_cvt<<<dim3(128, 16), tb, 0, stream>>>(Wk, WqT + 2097152, 512, 4096);
    transpose_cvt<<<dim3(128, 16), tb, 0, stream>>>(Wv, WqT + 4194304, 512, 4096);
    transpose_cvt<<<dim3(16, 128), tb, 0, stream>>>(Wo, WoT, 4096, 512);

    if (McA) {
        // ---- Plan A ----
        const int Mc = McA;
        u16* Ao  = (u16*)(ws + W);
        u16* Xb  = (u16*)(ws + W + AO);           // 3x [Mc][512]
        u16* Qc  = Xb + (size_t)3 * Mc * 512;     // 3x [Mc][4096]
        u16* Kc  = Qc + (size_t)Mc * 4096;
        u16* Vc  = Kc + (size_t)Mc * 4096;
        const dim3 gProj(16, Mc / 256, 3);
        for (int m0 = 0; m0 < N; m0 += Mc) {
            const long xoff = (long)m0 * 512;
            cvt3_bf16<<<dim3(Mc / 4, 1, 3), 256, 0, stream>>>(
                Xq + xoff, Xk + xoff, Xv + xoff, Xb, (long)Mc * 512);
            gemm256<0><<<gProj, 512, 0, stream>>>(Xb, WqT, Qc, nullptr,
                                                  Mc, 4096, 512,
                                                  (long)Mc * 512, 2097152L,
                                                  (long)Mc * 4096);
            attn_kernel<<<Mc, 256, 0, stream>>>(Qc, Kc, Vc, Ao + (long)m0 * 4096);
        }
        gemm256<1><<<dim3(2, 128, 1), 512, 0, stream>>>(
            Ao, WoT, d_out, bo, N, 512, 4096, 0L, 0L, 0L);
    } else {
        // ---- Plan B (streaming) ----
        int Mc = 8192;
        while (Mc > 256 && W + (size_t)Mc * 27648ull > ws_size) Mc >>= 1;
        if (W + (size_t)Mc * 27648ull > ws_size) return;
        u16* Xb = (u16*)(ws + W);
        u16* Qc = Xb + (size_t)3 * Mc * 512;
        u16* Kc = Qc + (size_t)Mc * 4096;
        u16* Vc = Kc + (size_t)Mc * 4096;
        const dim3 gProj(16, Mc / 256, 3);
        const dim3 gOut(2, Mc / 256, 1);
        for (int m0 = 0; m0 < N; m0 += Mc) {
            const long xoff = (long)m0 * 512;
            cvt3_bf16<<<dim3(Mc / 4, 1, 3), 256, 0, stream>>>(
                Xq + xoff, Xk + xoff, Xv + xoff, Xb, (long)Mc * 512);
            gemm256<0><<<gProj, 512, 0, stream>>>(Xb, WqT, Qc, nullptr,
                                                  Mc, 4096, 512,
                                                  (long)Mc * 512, 2097152L,
                                                  (long)Mc * 4096);
            attn_kernel<<<Mc, 256, 0, stream>>>(Qc, Kc, Vc, Qc);
            gemm256<1><<<gOut, 512, 0, stream>>>(Qc, WoT, (float*)d_out + xoff, bo,
                                                 Mc, 512, 4096, 0L, 0L, 0L);
        }
    }
}